// Round 4
// baseline (425.777 us; speedup 1.0000x reference)
//
#include <hip/hip_runtime.h>

// Problem constants (fixed by the reference)
#define MM 8192
#define NN 4096
#define KK 4096

// GEMM tiling: 256x256 block tile, BK=128 (4 K-steps of 32 per A-tile).
// A: LDS ring-4 (4 x 32KB = 128KB). B: global->register, no LDS.
#define BM 256
#define BN 256
#define BK 128
#define NT (KK / BK)          // 32 K-tiles
#define SLOT_BYTES 32768      // one A ring slot (256 rows x 128B)

typedef int int32x4  __attribute__((ext_vector_type(4)));
typedef int int32x16 __attribute__((ext_vector_type(16)));

// ---------------------------------------------------------------------------
// Async global->LDS, 16B per lane. LDS destination is wave-uniform base +
// lane*16 (m104/m108); global source address is per-lane free (carries the
// bank-conflict swizzle).
// ---------------------------------------------------------------------------
__device__ __forceinline__ void async_load16(const void* g, void* l) {
  __builtin_amdgcn_global_load_lds(
      (__attribute__((address_space(1))) void*)(void*)g,
      (__attribute__((address_space(3))) void*)l,
      16, 0, 0);
}

// ---------------------------------------------------------------------------
// Pack kernel: int32 (int8-range) -> int8, subtracting zero points.
// A8: row-major [M][K] (feeds LDS staging).
// W8: fragment-native layout [n>>5][k>>4][n&31][16] so that a GEMM B-fragment
//     load (32 n-rows x 16 k-bytes) is ONE fully coalesced 1KB wave read.
// 16 elements/thread. A threads: M*K/16 = 2,097,152; W threads: N*K/16 =
// 1,048,576; total 12288 blocks of 256 (exact, A/W boundary block-aligned).
// ---------------------------------------------------------------------------
__global__ __launch_bounds__(256) void pack_kernel(
    const int* __restrict__ a, const int* __restrict__ w,
    char* __restrict__ a8, char* __restrict__ w8,
    const int* __restrict__ izp, const int* __restrict__ wzp) {
  const long tid = (long)blockIdx.x * 256 + threadIdx.x;
  const long A_T = (long)MM * KK / 16;

  const int4* src;
  int4* dst;
  int z;
  if (tid < A_T) {
    src = (const int4*)a + tid * 4;
    dst = (int4*)a8 + tid;
    z = izp[0];
  } else {
    const long t = tid - A_T;            // 0 .. N*K/16-1
    const int nb  = (int)(t >> 13);      // n-group of 32   (8192 threads each)
    const int rem = (int)(t & 8191);
    const int kc  = rem >> 5;            // k-chunk of 16   (0..255)
    const int n5  = rem & 31;
    const int n   = nb * 32 + n5;
    src = (const int4*)(w + (long)n * KK + kc * 16);
    dst = (int4*)(w8 + (long)nb * 131072 + kc * 512 + n5 * 16);
    z = wzp[n];
  }

  int4 v0 = src[0], v1 = src[1], v2 = src[2], v3 = src[3];
  union { char c[16]; int4 q; } u;
  u.c[0]  = (char)(v0.x - z); u.c[1]  = (char)(v0.y - z);
  u.c[2]  = (char)(v0.z - z); u.c[3]  = (char)(v0.w - z);
  u.c[4]  = (char)(v1.x - z); u.c[5]  = (char)(v1.y - z);
  u.c[6]  = (char)(v1.z - z); u.c[7]  = (char)(v1.w - z);
  u.c[8]  = (char)(v2.x - z); u.c[9]  = (char)(v2.y - z);
  u.c[10] = (char)(v2.z - z); u.c[11] = (char)(v2.w - z);
  u.c[12] = (char)(v3.x - z); u.c[13] = (char)(v3.y - z);
  u.c[14] = (char)(v3.z - z); u.c[15] = (char)(v3.w - z);
  *dst = u.q;
}

// ---------------------------------------------------------------------------
// int8 GEMM, A-in-LDS (ring-4) + B-in-registers (flatmm style):
//   C[m][n] = sum_k A8[m][k] * W8[n][k];  out = is*ws[n]*C + bias[n]
//
// 256x256 tile, BK=128, 512 threads = 8 waves (2m x 4n), wave tile 128x64 =
// 4x2 of v_mfma_i32_32x32x32_i8, 4 K-steps per tile. Per tile per wave:
// 16 ds_read_b128 (A frags), 8 coalesced 1KB B loads (ping-pong reg sets,
// prefetch distance 1), 4 async_load16 (A stage, distance 3), 32 MFMA.
// LDS pipe per CU per tile ~= 16*8*12 + 256 = 1792 cy < matrix 2340 cy:
// matrix is now the only critical pipe (was co-saturated with LDS).
//
// Per-tile boundary: s_waitcnt vmcnt(24) lgkmcnt(0); s_barrier.
//  - vmcnt(24): drains every VMEM op issued >= 2 tiles ago (each tile issues
//    12: 8 B + 4 A-stage) => A(t+1) landed for ALL waves before anyone reads
//    slot (t+1)&3 after the barrier; newer 24 (tiles t-1, t) stay in flight.
//    Robust to intra-tile issue reorder by the compiler. Never drains to 0.
//  - lgkmcnt(0): own s3 frag-reads of slot t&3 are complete before the
//    barrier, so the A-stage(t+4) -> slot t&3 issued after the next barrier
//    cannot race any in-flight read.
//  - B-register consumption is compiler-tracked (plain loads): it inserts
//    counted waits before first use; prefetch distance ~2300cy >> latency.
//
// A-swizzle (round-0-proven class, zero conflicts): 128B row = 8 subs of
// 16B; physical sub p of row r holds logical p ^ (r&7), applied by permuting
// the per-lane GLOBAL source of async_load16. Fragment read step s: lane
// (m=r31, hi) reads logical sub 2s+hi of row m -> physical (2s+hi)^(r31&7);
// every 8 consecutive lanes hit 8 distinct 4-bank groups.
// ---------------------------------------------------------------------------
__global__ __launch_bounds__(512, 2) void qgemm_kernel(
    const char* __restrict__ A8, const char* __restrict__ W8,
    float* __restrict__ out,
    const float* __restrict__ bias,
    const float* __restrict__ is_ptr,
    const float* __restrict__ wscale) {
  __shared__ __attribute__((aligned(16))) char lds[4 * SLOT_BYTES];  // 128 KB

  // ---- block swizzle: XCD-bijective (512 blocks, 512%8==0, cpx=64) ------
  int pid = blockIdx.x;
  pid = (pid & 7) * 64 + (pid >> 3);
  const int bm = pid >> 4;  // 0..31
  const int bn = pid & 15;  // 0..15

  const int tid  = threadIdx.x;
  const int wid  = tid >> 6;
  const int lane = tid & 63;
  const int wm = (wid >> 2) * 128;  // 0 / 128
  const int wn = (wid & 3) * 64;    // 0 / 64 / 128 / 192

  // ---- A staging addresses ----------------------------------------------
  // A tile = 256 rows x 128B = 32 chunks of 1KB (8 rows each). Wave w stages
  // chunks {w, w+8, w+16, w+24}. Lane l -> row_in_chunk = l>>3, physical sub
  // = l&7, logical (global) sub = (l&7) ^ (l>>3).
  const int srow = lane >> 3;          // 0..7
  const int ssub = (lane & 7) ^ srow;
  const char* a_src[4];
  int c_off[4];
#pragma unroll
  for (int i = 0; i < 4; ++i) {
    const int c = wid + i * 8;  // chunk 0..31
    a_src[i] = A8 + (long)(bm * BM + c * 8 + srow) * KK + ssub * 16;
    c_off[i] = c * 1024;
  }

#define STAGE_A4(T)                                                          \
  {                                                                          \
    char* sl_ = lds + ((T) & 3) * SLOT_BYTES;                                \
    async_load16(a_src[0] + (T) * BK, sl_ + c_off[0]);                       \
    async_load16(a_src[1] + (T) * BK, sl_ + c_off[1]);                       \
    async_load16(a_src[2] + (T) * BK, sl_ + c_off[2]);                       \
    async_load16(a_src[3] + (T) * BK, sl_ + c_off[3]);                       \
  }

  // ---- fragment addressing ----------------------------------------------
  const int r31 = lane & 31;
  const int hi  = lane >> 5;
  const int ps0 = ((0 + hi) ^ (r31 & 7)) * 16;
  const int ps1 = ((2 + hi) ^ (r31 & 7)) * 16;
  const int ps2 = ((4 + hi) ^ (r31 & 7)) * 16;
  const int ps3 = ((6 + hi) ^ (r31 & 7)) * 16;
  const int a_row = (wm + r31) * BK;   // byte offset of lane's A row

  // B pointers: fragment-native layout [nb][kc][n5][16]; lane reads 16B at
  // nb*131072 + (t*8 + s*2 + hi)*512 + r31*16 -> wave = contiguous 1KB.
  const char* b_ptr[2];
#pragma unroll
  for (int ni = 0; ni < 2; ++ni) {
    const int nbg = (bn * BN + wn + ni * 32) >> 5;
    b_ptr[ni] = W8 + (long)nbg * 131072 + hi * 512 + r31 * 16;
  }

#define LOAD_B(SET, T)                                                       \
  {                                                                          \
    SET[0][0] = *(const int32x4*)(b_ptr[0] + (T) * 4096 + 0 * 1024);         \
    SET[0][1] = *(const int32x4*)(b_ptr[0] + (T) * 4096 + 1 * 1024);         \
    SET[0][2] = *(const int32x4*)(b_ptr[0] + (T) * 4096 + 2 * 1024);         \
    SET[0][3] = *(const int32x4*)(b_ptr[0] + (T) * 4096 + 3 * 1024);         \
    SET[1][0] = *(const int32x4*)(b_ptr[1] + (T) * 4096 + 0 * 1024);         \
    SET[1][1] = *(const int32x4*)(b_ptr[1] + (T) * 4096 + 1 * 1024);         \
    SET[1][2] = *(const int32x4*)(b_ptr[1] + (T) * 4096 + 2 * 1024);         \
    SET[1][3] = *(const int32x4*)(b_ptr[1] + (T) * 4096 + 3 * 1024);         \
  }

#define READ_A(DST, T, PS)                                                   \
  {                                                                          \
    const char* ar_ = lds + ((T) & 3) * SLOT_BYTES + a_row;                  \
    DST[0] = *(const int32x4*)(ar_ + 0 * 4096 + (PS));                       \
    DST[1] = *(const int32x4*)(ar_ + 1 * 4096 + (PS));                       \
    DST[2] = *(const int32x4*)(ar_ + 2 * 4096 + (PS));                       \
    DST[3] = *(const int32x4*)(ar_ + 3 * 4096 + (PS));                       \
  }

  int32x16 acc[4][2];
#pragma unroll
  for (int mi = 0; mi < 4; ++mi)
#pragma unroll
    for (int ni = 0; ni < 2; ++ni) acc[mi][ni] = (int32x16)0;

  int32x4 a0[4], a1[4];        // A frag ping-pong (step-level)
  int32x4 bE[2][4], bO[2][4];  // B reg sets, tile-parity ping-pong

#define MFMA8(AF, BSET, S)                                                   \
  {                                                                          \
    __builtin_amdgcn_s_setprio(1);                                           \
    acc[0][0] = __builtin_amdgcn_mfma_i32_32x32x32_i8(AF[0], BSET[0][S], acc[0][0], 0, 0, 0); \
    acc[0][1] = __builtin_amdgcn_mfma_i32_32x32x32_i8(AF[0], BSET[1][S], acc[0][1], 0, 0, 0); \
    acc[1][0] = __builtin_amdgcn_mfma_i32_32x32x32_i8(AF[1], BSET[0][S], acc[1][0], 0, 0, 0); \
    acc[1][1] = __builtin_amdgcn_mfma_i32_32x32x32_i8(AF[1], BSET[1][S], acc[1][1], 0, 0, 0); \
    acc[2][0] = __builtin_amdgcn_mfma_i32_32x32x32_i8(AF[2], BSET[0][S], acc[2][0], 0, 0, 0); \
    acc[2][1] = __builtin_amdgcn_mfma_i32_32x32x32_i8(AF[2], BSET[1][S], acc[2][1], 0, 0, 0); \
    acc[3][0] = __builtin_amdgcn_mfma_i32_32x32x32_i8(AF[3], BSET[0][S], acc[3][0], 0, 0, 0); \
    acc[3][1] = __builtin_amdgcn_mfma_i32_32x32x32_i8(AF[3], BSET[1][S], acc[3][1], 0, 0, 0); \
    __builtin_amdgcn_s_setprio(0);                                           \
  }

  // One tile: consume A(t) from LDS + BCUR; prefetch B(t+1)->BNXT, A(t+3).
#define TILE_BODY(T, BCUR, BNXT)                                             \
  {                                                                          \
    const int t_ = (T);                                                      \
    if (t_ + 1 < NT) LOAD_B(BNXT, t_ + 1);                                   \
    if (t_ + 3 < NT) STAGE_A4(t_ + 3);                                       \
    READ_A(a1, t_, ps1);                                                     \
    MFMA8(a0, BCUR, 0);                                                      \
    READ_A(a0, t_, ps2);                                                     \
    MFMA8(a1, BCUR, 1);                                                      \
    READ_A(a1, t_, ps3);                                                     \
    MFMA8(a0, BCUR, 2);                                                      \
    asm volatile("s_waitcnt vmcnt(24) lgkmcnt(0)" ::: "memory");             \
    __builtin_amdgcn_s_barrier();                                            \
    if (t_ + 1 < NT) READ_A(a0, t_ + 1, ps0);                                \
    MFMA8(a1, BCUR, 3);                                                      \
  }

  // ---- prologue: stage A(0..2), load B(0); wait A(0); read first frags --
  STAGE_A4(0);
  STAGE_A4(1);
  STAGE_A4(2);
  LOAD_B(bE, 0);
  asm volatile("s_waitcnt vmcnt(16)" ::: "memory");  // A(0) landed
  __builtin_amdgcn_s_barrier();
  READ_A(a0, 0, ps0);

  // ---- main loop: 2 tiles per iteration (B set parity is static) --------
  for (int u = 0; u < NT / 2; ++u) {
    TILE_BODY(2 * u,     bE, bO);
    TILE_BODY(2 * u + 1, bO, bE);
  }

  // ---- epilogue: out = is * ws[n] * acc + bias[n] -----------------------
  // C/D layout (32x32): col = lane&31, row = (r&3) + 8*(r>>2) + 4*(lane>>5)
  const float is0 = is_ptr[0];
  const int row_base = bm * BM + wm + 4 * hi;
  const int col_base = bn * BN + wn + r31;
#pragma unroll
  for (int ni = 0; ni < 2; ++ni) {
    const int col = col_base + ni * 32;
    const float s = is0 * wscale[col];
    const float b = bias[col];
#pragma unroll
    for (int mi = 0; mi < 4; ++mi) {
      const long rb = (long)(row_base + mi * 32) * NN + col;
#pragma unroll
      for (int r = 0; r < 16; ++r) {
        const int roff = (r & 3) + 8 * (r >> 2);
        out[rb + (long)roff * NN] = (float)acc[mi][ni][r] * s + b;
      }
    }
  }
#undef TILE_BODY
#undef MFMA8
#undef READ_A
#undef LOAD_B
#undef STAGE_A4
}

// ---------------------------------------------------------------------------
extern "C" void kernel_launch(void* const* d_in, const int* in_sizes, int n_in,
                              void* d_out, int out_size, void* d_ws, size_t ws_size,
                              hipStream_t stream) {
  const int*   inp    = (const int*)d_in[0];    // [M,K] int32 (int8-range)
  const int*   weight = (const int*)d_in[1];    // [N,K] int32 (int8-range)
  const float* bias   = (const float*)d_in[2];  // [N]
  const float* iscale = (const float*)d_in[3];  // [1]
  const int*   izp    = (const int*)d_in[4];    // [1]
  const float* wscale = (const float*)d_in[5];  // [N]
  const int*   wzp    = (const int*)d_in[6];    // [N]
  float* out = (float*)d_out;

  char* a8 = (char*)d_ws;                        // M*K  = 33.5 MB, row-major
  char* w8 = a8 + (size_t)MM * KK;               // N*K  = 16.8 MB, frag-native

  // pack: (M*K + N*K)/16 threads -> 12288 blocks of 256 (exact)
  pack_kernel<<<12288, 256, 0, stream>>>(inp, weight, a8, w8, izp, wzp);

  // GEMM: 32 * 16 = 512 blocks of 512 threads (8 waves), 1 block/CU
  qgemm_kernel<<<512, 512, 0, stream>>>(a8, w8, out, bias, iscale, wscale);
}

// Round 5
// 413.553 us; speedup vs baseline: 1.0296x; 1.0296x over previous
//
#include <hip/hip_runtime.h>

// Problem constants (fixed by the reference)
#define MM 8192
#define NN 4096
#define KK 4096

// GEMM tiling: 128x256 block tile, BK=64, ring-3 LDS, 4 waves (2m x 2n),
// wave tile 64x128 = 2x4 of v_mfma_i32_32x32x32_i8.
#define BM 128
#define BN 256
#define BK 64
#define NT (KK / BK)          // 64 K-tiles
#define A_BYTES (BM * BK)     // 8 KB
#define B_BYTES (BN * BK)     // 16 KB
#define SLOT (A_BYTES + B_BYTES)  // 24 KB; ring-3 = 72 KB -> 2 blocks/CU

typedef int int32x4  __attribute__((ext_vector_type(4)));
typedef int int32x16 __attribute__((ext_vector_type(16)));

// ---------------------------------------------------------------------------
// Async global->LDS, 16B per lane. LDS destination is wave-uniform base +
// lane*16 (m104/m108); global source address is per-lane free (carries the
// bank-conflict swizzle).
// ---------------------------------------------------------------------------
__device__ __forceinline__ void async_load16(const void* g, void* l) {
  __builtin_amdgcn_global_load_lds(
      (__attribute__((address_space(1))) void*)(void*)g,
      (__attribute__((address_space(3))) void*)l,
      16, 0, 0);
}

// ---------------------------------------------------------------------------
// Pack kernel (round-0 proven version): int32 (int8-range) -> int8,
// subtracting zero points. 4 elements/thread: ONE int4 load (16B/lane,
// wave reads 1KB contiguous) -> pack -> one 4B store (wave 256B contiguous).
//   A: M*K/4 threads -> 32768 blocks of 256; W: N*K/4 -> 16384 blocks.
// A/W boundary is block-aligned.
// ---------------------------------------------------------------------------
__global__ __launch_bounds__(256) void pack_kernel(
    const int* __restrict__ a, const int* __restrict__ w,
    char* __restrict__ a8, char* __restrict__ w8,
    const int* __restrict__ izp, const int* __restrict__ wzp) {
  const long tid = (long)blockIdx.x * 256 + threadIdx.x;
  const long A_T = (long)MM * KK / 4;

  const int4* src;
  int* dst;
  int z;
  if (tid < A_T) {
    src = (const int4*)a + tid;
    dst = (int*)a8 + tid;
    z = izp[0];
  } else {
    long t = tid - A_T;
    src = (const int4*)w + t;
    dst = (int*)w8 + t;
    z = wzp[t >> 10];  // K/4 = 1024 threads per weight row
  }

  int4 v = *src;
  union { char c[4]; int q; } u;
  u.c[0] = (char)(v.x - z);
  u.c[1] = (char)(v.y - z);
  u.c[2] = (char)(v.z - z);
  u.c[3] = (char)(v.w - z);
  *dst = u.q;
}

// ---------------------------------------------------------------------------
// int8 GEMM, m201-faithful phase template + ring-3 + 2 blocks/CU:
//   C[m][n] = sum_k A8[m][k] * W8[n][k];  out = is*ws[n]*C + bias[n]
//
// 4 waves (2m x 2n), wave tile 64x128: acc[2][4] of 32x32, 16 MFMA per
// K-tile per wave (2 kk-phases of 8). LDS ring-3 of 24KB slots; tile t
// reads slot t%3, stages tile t+2 into slot (t+2)%3 (prefetch distance 2
// = ~1500cy margin; round-1's failure was a 1-phase margin).
//
// Per phase: { 6 ds_read_b128 ; 3 async_load16(t+2) ; s_barrier ;
//   sched_barrier(0)  [rule18: pin MFMA after barrier; compiler emits
//   COUNTED lgkmcnt before each MFMA] ; setprio(1) ; 8 MFMA ; setprio(0);
//   s_barrier }
// Boundary: vmcnt(6) before phase-1's mid barrier: newest 6 VMEM ops are
// tile t+2's -> all of tile t+1 has landed for every wave once the barrier
// releases. Never drains to 0 in the main loop.
// WAR on slot reuse: stage(t+2) overwrites slot (t-1)%3; every wave's reads
// of t-1 completed before t-1's closing barrier (lgkm waits precede its
// MFMAs), one full tile before the stage issues. No timing assumptions.
//
// Swizzle (rounds 2/3-proven, 64B rows = 4 subs of 16B): physical sub p of
// row r holds logical p ^ ((r>>1)&3), applied via the per-lane GLOBAL source
// of async_load16 (LDS dest linear). Frag read phase kk: lane(m=r31,hi)
// wants logical 2kk+hi of row m -> physical (2kk+hi)^((r31>>1)&3); every 8
// consecutive lanes hit 8 distinct 4-bank groups (checked by enumeration).
//
// Occupancy: 256 thr, ~200 VGPR (launch_bounds cap 2 waves/SIMD), 72KB LDS
// -> 2 independent blocks/CU: their unsynced phases stagger, so one block's
// MFMA clusters overlap the other's LDS/stage phases (m114 mechanism).
// ---------------------------------------------------------------------------
__global__ __launch_bounds__(256, 2) void qgemm_kernel(
    const char* __restrict__ A8, const char* __restrict__ W8,
    float* __restrict__ out,
    const float* __restrict__ bias,
    const float* __restrict__ is_ptr,
    const float* __restrict__ wscale) {
  __shared__ __attribute__((aligned(16))) char lds[3 * SLOT];  // 72 KB

  // ---- block swizzle: XCD-bijective (1024 blocks, cpx=128) --------------
  // XCD x owns tile-ids [128x,128x+128) -> bm in [8x,8x+8): 8 A-panels
  // (4MB) L2-resident per XCD; B (16.8MB) streams via L3.
  int pid = blockIdx.x;
  pid = (pid & 7) * 128 + (pid >> 3);
  const int bm = pid >> 4;  // 0..63
  const int bn = pid & 15;  // 0..15

  const int tid  = threadIdx.x;
  const int wid  = tid >> 6;
  const int lane = tid & 63;
  const int wm = (wid & 1) * 64;    // 0 / 64
  const int wn = (wid >> 1) * 128;  // 0 / 128

  // ---- staging addresses ------------------------------------------------
  // Chunk = 16 rows x 64B = 1KB. A tile: 8 chunks, wave w stages {w, w+4}.
  // B tile: 16 chunks, wave w stages {w, w+4, w+8, w+12}.
  // Lane l -> row_in_chunk = l>>2, physical sub = l&3,
  //           logical (global) sub = (l&3) ^ ((l>>3)&3)   [row>>1 == l>>3]
  const int srow = lane >> 2;
  const int ssub = (lane & 3) ^ ((lane >> 3) & 3);
  const char* a_src[2];
  const char* b_src[4];
  int a_off[2], b_off[4];
#pragma unroll
  for (int i = 0; i < 2; ++i) {
    const int c = wid + i * 4;  // 0..7
    a_src[i] = A8 + (long)(bm * BM + c * 16 + srow) * KK + ssub * 16;
    a_off[i] = c * 1024;
  }
#pragma unroll
  for (int j = 0; j < 4; ++j) {
    const int c = wid + j * 4;  // 0..15
    b_src[j] = W8 + (long)(bn * BN + c * 16 + srow) * KK + ssub * 16;
    b_off[j] = c * 1024;
  }

#define STAGE_A(I, T, SS) \
  async_load16(a_src[I] + (T) * BK, lds + (SS) + a_off[I])
#define STAGE_B(J, T, SS) \
  async_load16(b_src[J] + (T) * BK, lds + (SS) + A_BYTES + b_off[J])

  // ---- fragment read addressing -----------------------------------------
  const int r31 = lane & 31;
  const int hi  = lane >> 5;
  const int rx  = (r31 >> 1) & 3;
  const int ps0 = ((0 + hi) ^ rx) * 16;  // kk=0
  const int ps1 = ((2 + hi) ^ rx) * 16;  // kk=1
  const int a_row = (wm + r31) * BK;
  const int b_row = (wn + r31) * BK;

  int32x16 acc[2][4];
#pragma unroll
  for (int mi = 0; mi < 2; ++mi)
#pragma unroll
    for (int ni = 0; ni < 4; ++ni) acc[mi][ni] = (int32x16)0;

  int32x4 af0, af1, bf0, bf1, bf2, bf3;

#define READ_FRAGS(SR, PS)                                                   \
  {                                                                          \
    const char* ar_ = lds + (SR) + a_row;                                    \
    const char* br_ = lds + (SR) + A_BYTES + b_row;                          \
    af0 = *(const int32x4*)(ar_ + 0 * 2048 + (PS));                          \
    af1 = *(const int32x4*)(ar_ + 1 * 2048 + (PS));                          \
    bf0 = *(const int32x4*)(br_ + 0 * 2048 + (PS));                          \
    bf1 = *(const int32x4*)(br_ + 1 * 2048 + (PS));                          \
    bf2 = *(const int32x4*)(br_ + 2 * 2048 + (PS));                          \
    bf3 = *(const int32x4*)(br_ + 3 * 2048 + (PS));                          \
  }

#define MFMA_PHASE()                                                         \
  {                                                                          \
    __builtin_amdgcn_sched_barrier(0);                                       \
    __builtin_amdgcn_s_setprio(1);                                           \
    acc[0][0] = __builtin_amdgcn_mfma_i32_32x32x32_i8(af0, bf0, acc[0][0], 0, 0, 0); \
    acc[0][1] = __builtin_amdgcn_mfma_i32_32x32x32_i8(af0, bf1, acc[0][1], 0, 0, 0); \
    acc[0][2] = __builtin_amdgcn_mfma_i32_32x32x32_i8(af0, bf2, acc[0][2], 0, 0, 0); \
    acc[0][3] = __builtin_amdgcn_mfma_i32_32x32x32_i8(af0, bf3, acc[0][3], 0, 0, 0); \
    acc[1][0] = __builtin_amdgcn_mfma_i32_32x32x32_i8(af1, bf0, acc[1][0], 0, 0, 0); \
    acc[1][1] = __builtin_amdgcn_mfma_i32_32x32x32_i8(af1, bf1, acc[1][1], 0, 0, 0); \
    acc[1][2] = __builtin_amdgcn_mfma_i32_32x32x32_i8(af1, bf2, acc[1][2], 0, 0, 0); \
    acc[1][3] = __builtin_amdgcn_mfma_i32_32x32x32_i8(af1, bf3, acc[1][3], 0, 0, 0); \
    __builtin_amdgcn_s_setprio(0);                                           \
  }

  // Full tile: read slot SR (= t%3 * SLOT), stage tile T+2 into slot SS.
#define TILE_FULL(T, SR, SS)                                                 \
  {                                                                          \
    /* phase 0 (kk=0): reads ; stage A(t+2)+B0 ; barrier ; MFMA ; barrier */ \
    READ_FRAGS(SR, ps0);                                                     \
    STAGE_A(0, (T) + 2, SS); STAGE_A(1, (T) + 2, SS);                        \
    STAGE_B(0, (T) + 2, SS);                                                 \
    __builtin_amdgcn_s_barrier();                                            \
    MFMA_PHASE();                                                            \
    __builtin_amdgcn_s_barrier();                                            \
    /* phase 1 (kk=1): reads ; stage B1..3(t+2) ; vmcnt(6) ; barrier ... */  \
    READ_FRAGS(SR, ps1);                                                     \
    STAGE_B(1, (T) + 2, SS); STAGE_B(2, (T) + 2, SS);                        \
    STAGE_B(3, (T) + 2, SS);                                                 \
    asm volatile("s_waitcnt vmcnt(6)" ::: "memory");                         \
    __builtin_amdgcn_s_barrier();                                            \
    MFMA_PHASE();                                                            \
    __builtin_amdgcn_s_barrier();                                            \
  }

  // Tail tile: no staging, no vmcnt (all data resident).
#define TILE_TAIL(SR)                                                        \
  {                                                                          \
    READ_FRAGS(SR, ps0);                                                     \
    __builtin_amdgcn_s_barrier();                                            \
    MFMA_PHASE();                                                            \
    __builtin_amdgcn_s_barrier();                                            \
    READ_FRAGS(SR, ps1);                                                     \
    __builtin_amdgcn_s_barrier();                                            \
    MFMA_PHASE();                                                            \
    __builtin_amdgcn_s_barrier();                                            \
  }

  // ---- prologue: stage tiles 0,1 (slots 0,1); wait tile 0 ---------------
  STAGE_A(0, 0, 0); STAGE_A(1, 0, 0);
  STAGE_B(0, 0, 0); STAGE_B(1, 0, 0); STAGE_B(2, 0, 0); STAGE_B(3, 0, 0);
  STAGE_A(0, 1, SLOT); STAGE_A(1, 1, SLOT);
  STAGE_B(0, 1, SLOT); STAGE_B(1, 1, SLOT);
  STAGE_B(2, 1, SLOT); STAGE_B(3, 1, SLOT);
  asm volatile("s_waitcnt vmcnt(6)" ::: "memory");  // tile 0 landed
  __builtin_amdgcn_s_barrier();

  // ---- main loop: tiles 0..59 (x3 unrolled for static ring slots) -------
  for (int u = 0; u < 60; u += 3) {
    TILE_FULL(u + 0, 0 * SLOT, 2 * SLOT);
    TILE_FULL(u + 1, 1 * SLOT, 0 * SLOT);
    TILE_FULL(u + 2, 2 * SLOT, 1 * SLOT);
  }
  // tiles 60,61 still stage (62 -> slot 2, 63 -> slot 0)
  TILE_FULL(60, 0 * SLOT, 2 * SLOT);
  TILE_FULL(61, 1 * SLOT, 0 * SLOT);
  // drain the last 6 loads (tile 63) once, then the two tail tiles
  asm volatile("s_waitcnt vmcnt(0)" ::: "memory");
  __builtin_amdgcn_s_barrier();
  TILE_TAIL(2 * SLOT);  // tile 62
  TILE_TAIL(0 * SLOT);  // tile 63

  // ---- epilogue: out = is * ws[n] * acc + bias[n] -----------------------
  // C/D layout (32x32): col = lane&31, row = (r&3) + 8*(r>>2) + 4*(lane>>5)
  const float is0 = is_ptr[0];
  const int row_base = bm * BM + wm + 4 * hi;
  const int col_base = bn * BN + wn + r31;
#pragma unroll
  for (int ni = 0; ni < 4; ++ni) {
    const int col = col_base + ni * 32;
    const float s = is0 * wscale[col];
    const float b = bias[col];
#pragma unroll
    for (int mi = 0; mi < 2; ++mi) {
      const long rb = (long)(row_base + mi * 32) * NN + col;
#pragma unroll
      for (int r = 0; r < 16; ++r) {
        const int roff = (r & 3) + 8 * (r >> 2);
        out[rb + (long)roff * NN] = (float)acc[mi][ni][r] * s + b;
      }
    }
  }
#undef TILE_TAIL
#undef TILE_FULL
#undef MFMA_PHASE
#undef READ_FRAGS
#undef STAGE_A
#undef STAGE_B
}

// ---------------------------------------------------------------------------
extern "C" void kernel_launch(void* const* d_in, const int* in_sizes, int n_in,
                              void* d_out, int out_size, void* d_ws, size_t ws_size,
                              hipStream_t stream) {
  const int*   inp    = (const int*)d_in[0];    // [M,K] int32 (int8-range)
  const int*   weight = (const int*)d_in[1];    // [N,K] int32 (int8-range)
  const float* bias   = (const float*)d_in[2];  // [N]
  const float* iscale = (const float*)d_in[3];  // [1]
  const int*   izp    = (const int*)d_in[4];    // [1]
  const float* wscale = (const float*)d_in[5];  // [N]
  const int*   wzp    = (const int*)d_in[6];    // [N]
  float* out = (float*)d_out;

  char* a8 = (char*)d_ws;                        // M*K  = 33.5 MB, row-major
  char* w8 = a8 + (size_t)MM * KK;               // N*K  = 16.8 MB, row-major

  // pack: (M*K + N*K)/4 threads = 12,582,912 -> 49152 blocks of 256 (exact)
  pack_kernel<<<49152, 256, 0, stream>>>(inp, weight, a8, w8, izp, wzp);

  // GEMM: 64 * 16 = 1024 blocks of 256 threads (4 waves), 2 blocks/CU
  qgemm_kernel<<<1024, 256, 0, stream>>>(a8, w8, out, bias, iscale, wscale);
}

// Round 6
// 402.288 us; speedup vs baseline: 1.0584x; 1.0280x over previous
//
#include <hip/hip_runtime.h>

// Problem constants (fixed by the reference)
#define MM 8192
#define NN 4096
#define KK 4096

// GEMM tiling: 256x256 block tile, BK=64, 4 waves of 128x128 (4x4 MFMA grid),
// ring-4 LDS, distance-3 staging, 1-phase register read-ahead.
#define BM 256
#define BN 256
#define BK 64
#define NT (KK / BK)          // 64 K-tiles
#define A_BYTES (BM * BK)     // 16 KB
#define SLOT 32768            // 16KB A + 16KB B; ring-4 = 128 KB

typedef int int32x4  __attribute__((ext_vector_type(4)));
typedef int int32x16 __attribute__((ext_vector_type(16)));

// ---------------------------------------------------------------------------
// Async global->LDS, 16B per lane. LDS destination is wave-uniform base +
// lane*16 (m104/m108); global source address is per-lane free (carries the
// bank-conflict swizzle).
// ---------------------------------------------------------------------------
__device__ __forceinline__ void async_load16(const void* g, void* l) {
  __builtin_amdgcn_global_load_lds(
      (__attribute__((address_space(1))) void*)(void*)g,
      (__attribute__((address_space(3))) void*)l,
      16, 0, 0);
}

// ---------------------------------------------------------------------------
// Pack kernel (round-0 proven version): int32 (int8-range) -> int8,
// subtracting zero points. 4 elements/thread: ONE int4 load -> pack -> one
// 4B store. A/W boundary is block-aligned.
// ---------------------------------------------------------------------------
__global__ __launch_bounds__(256) void pack_kernel(
    const int* __restrict__ a, const int* __restrict__ w,
    char* __restrict__ a8, char* __restrict__ w8,
    const int* __restrict__ izp, const int* __restrict__ wzp) {
  const long tid = (long)blockIdx.x * 256 + threadIdx.x;
  const long A_T = (long)MM * KK / 4;

  const int4* src;
  int* dst;
  int z;
  if (tid < A_T) {
    src = (const int4*)a + tid;
    dst = (int*)a8 + tid;
    z = izp[0];
  } else {
    long t = tid - A_T;
    src = (const int4*)w + t;
    dst = (int*)w8 + t;
    z = wzp[t >> 10];  // K/4 = 1024 threads per weight row
  }

  int4 v = *src;
  union { char c[4]; int q; } u;
  u.c[0] = (char)(v.x - z);
  u.c[1] = (char)(v.y - z);
  u.c[2] = (char)(v.z - z);
  u.c[3] = (char)(v.w - z);
  *dst = u.q;
}

// ---------------------------------------------------------------------------
// int8 GEMM, 1-phase register read-ahead + ring-4 counted-vmcnt:
//   C[m][n] = sum_k A8[m][k] * W8[n][k];  out = is*ws[n]*C + bias[n]
//
// 4 waves (2m x 2n), each 128x128 = 4x4 of v_mfma_i32_32x32x32_i8 (256 acc
// VGPR, 1 wave/SIMD). Read:MFMA ratio 8:16 per phase (was 6:8) -> per-CU LDS
// read cycles drop 33%, making LDS (~68us) ~ MFMA (~62.5us) balanced.
//
// Tile body S_t (sections pinned by sched_barrier(0); ONE barrier per tile):
//   [ STAGE8(t+3) ; ds_read (t,k1)->aN/bN ]    // sec 1
//   [ MFMA16 on aC/bC = (t,k0) ]               // sec 2: frags read LAST phase
//   [ ds_read (t+1,k0)->aC/bC ]                // sec 3: slot t+1 certified
//   [ MFMA16 on aN/bN = (t,k1) ]               // sec 4: frags from sec 1
//   vmcnt(8) ; s_barrier                       // boundary
// Every MFMA cluster consumes fragments issued one phase (~600cy) earlier;
// each read batch drains under the opposite MFMA cluster. No swap needed:
// aC/bC always hold k0, aN/bN k1 (all-static indexing, rule 20).
//
// Certification (count-exact, no timing assumptions): stage(s) issues at top
// of S_{s-3}. At S_t's boundary, outstanding = stage(t+2)[8, old] +
// stage(t+3)[8, new]; vmcnt(8) drains stage(t+2) => entering S_{t+1}, slots
// <= t+2 are landed for ALL waves (each wave drained its own, barrier joins).
// So S_t's reads of slot t (sec 1) and t+1 (sec 3) are certified. Never
// drains to 0 in the main loop; stage(t+2) was issued 2 tiles (~2400cy) ago.
// WAR on slot reuse: stage(t+3) writes slot (t-1)&3; last reads of t-1 were
// sec-1 of S_{t-1}, retired before that wave's sec-4 MFMAs (lgkm), which
// precede B(t); stage(t+3) is issued after B(t). Tail (t>=61): one vmcnt(0)
// (stage(63) issued 1 tile prior), then 3 barrier-free resident tiles.
//
// Swizzle (proven class, 64B rows = 4 subs of 16B): physical sub p of row r
// holds logical p ^ ((r>>1)&3) via per-lane GLOBAL source permutation of
// async_load16 (LDS dest linear). Frag read step kk: lane(m=r31,hi) wants
// logical 2kk+hi of row m -> physical (2kk+hi)^((r31>>1)&3); every 8
// consecutive lanes hit 8 distinct 16B bank groups (verified by enumeration).
// ---------------------------------------------------------------------------
__global__ __launch_bounds__(256, 1) void qgemm_kernel(
    const char* __restrict__ A8, const char* __restrict__ W8,
    float* __restrict__ out,
    const float* __restrict__ bias,
    const float* __restrict__ is_ptr,
    const float* __restrict__ wscale) {
  __shared__ __attribute__((aligned(16))) char lds[4 * SLOT];  // 128 KB

  // ---- block swizzle: XCD-bijective (512 blocks, cpx=64) ----------------
  int pid = blockIdx.x;
  pid = (pid & 7) * 64 + (pid >> 3);
  const int bm = pid >> 4;  // 0..31
  const int bn = pid & 15;  // 0..15

  const int tid  = threadIdx.x;
  const int wid  = tid >> 6;
  const int lane = tid & 63;
  const int wm = (wid & 1) * 128;   // 0 / 128
  const int wn = (wid >> 1) * 128;  // 0 / 128

  // ---- staging addresses ------------------------------------------------
  // A tile = 256 rows x 64B = 16 chunks of 1KB (16 rows); wave w stages
  // chunks {w, w+4, w+8, w+12}; same for B.
  // Lane l -> row_in_chunk = l>>2, physical sub = l&3,
  //           logical (global) sub = (l&3) ^ ((l>>3)&3)   [row>>1 == l>>3]
  const int srow = lane >> 2;
  const int ssub = (lane & 3) ^ ((lane >> 3) & 3);
  const char* a_src[4];
  const char* b_src[4];
  int c_off[4];
#pragma unroll
  for (int i = 0; i < 4; ++i) {
    const int c = wid + i * 4;  // chunk 0..15
    a_src[i] = A8 + (long)(bm * BM + c * 16 + srow) * KK + ssub * 16;
    b_src[i] = W8 + (long)(bn * BN + c * 16 + srow) * KK + ssub * 16;
    c_off[i] = c * 1024;
  }

#define STAGE8(T)                                                            \
  {                                                                          \
    char* sl_ = lds + ((T) & 3) * SLOT;                                      \
    async_load16(a_src[0] + (T) * BK, sl_ + c_off[0]);                       \
    async_load16(a_src[1] + (T) * BK, sl_ + c_off[1]);                       \
    async_load16(a_src[2] + (T) * BK, sl_ + c_off[2]);                       \
    async_load16(a_src[3] + (T) * BK, sl_ + c_off[3]);                       \
    async_load16(b_src[0] + (T) * BK, sl_ + A_BYTES + c_off[0]);             \
    async_load16(b_src[1] + (T) * BK, sl_ + A_BYTES + c_off[1]);             \
    async_load16(b_src[2] + (T) * BK, sl_ + A_BYTES + c_off[2]);             \
    async_load16(b_src[3] + (T) * BK, sl_ + A_BYTES + c_off[3]);             \
  }

  // ---- fragment read addressing -----------------------------------------
  const int r31 = lane & 31;
  const int hi  = lane >> 5;
  const int rx  = (r31 >> 1) & 3;
  const int ps0 = ((0 + hi) ^ rx) * 16;  // kk=0
  const int ps1 = ((2 + hi) ^ rx) * 16;  // kk=1
  const int a_row = (wm + r31) * BK;
  const int b_row = (wn + r31) * BK;

#define READ8(AF, BF, T, PS)                                                 \
  {                                                                          \
    const char* ar_ = lds + ((T) & 3) * SLOT + a_row;                        \
    const char* br_ = lds + ((T) & 3) * SLOT + A_BYTES + b_row;              \
    AF[0] = *(const int32x4*)(ar_ + 0 * 2048 + (PS));                        \
    AF[1] = *(const int32x4*)(ar_ + 1 * 2048 + (PS));                        \
    AF[2] = *(const int32x4*)(ar_ + 2 * 2048 + (PS));                        \
    AF[3] = *(const int32x4*)(ar_ + 3 * 2048 + (PS));                        \
    BF[0] = *(const int32x4*)(br_ + 0 * 2048 + (PS));                        \
    BF[1] = *(const int32x4*)(br_ + 1 * 2048 + (PS));                        \
    BF[2] = *(const int32x4*)(br_ + 2 * 2048 + (PS));                        \
    BF[3] = *(const int32x4*)(br_ + 3 * 2048 + (PS));                        \
  }

  int32x16 acc[4][4];
#pragma unroll
  for (int mi = 0; mi < 4; ++mi)
#pragma unroll
    for (int ni = 0; ni < 4; ++ni) acc[mi][ni] = (int32x16)0;

  int32x4 aC[4], bC[4];  // k0 operands (read one phase ahead)
  int32x4 aN[4], bN[4];  // k1 operands

#define MFMA16(AF, BF)                                                       \
  {                                                                          \
    _Pragma("unroll")                                                        \
    for (int mi = 0; mi < 4; ++mi)                                           \
      _Pragma("unroll")                                                      \
      for (int ni = 0; ni < 4; ++ni)                                         \
        acc[mi][ni] = __builtin_amdgcn_mfma_i32_32x32x32_i8(                 \
            AF[mi], BF[ni], acc[mi][ni], 0, 0, 0);                           \
  }

#define SBAR() __builtin_amdgcn_sched_barrier(0)

#define FULL_BODY(T)                                                         \
  {                                                                          \
    STAGE8((T) + 3);                                                         \
    READ8(aN, bN, (T), ps1);                                                 \
    SBAR();                                                                  \
    MFMA16(aC, bC); /* (t,k0) */                                             \
    SBAR();                                                                  \
    READ8(aC, bC, (T) + 1, ps0);                                             \
    SBAR();                                                                  \
    MFMA16(aN, bN); /* (t,k1) */                                             \
    SBAR();                                                                  \
    asm volatile("s_waitcnt vmcnt(8)" ::: "memory");                         \
    __builtin_amdgcn_s_barrier();                                            \
  }

  // ---- prologue: stage 0,1,2; certify slots 0,1; preload (0,k0) ---------
  STAGE8(0);
  STAGE8(1);
  STAGE8(2);
  asm volatile("s_waitcnt vmcnt(8)" ::: "memory");  // drains stage(0),(1)
  __builtin_amdgcn_s_barrier();
  READ8(aC, bC, 0, ps0);

  // ---- main loop: t = 0..59 (stages 3..62), then t=60 (stages 63) -------
#pragma unroll 4
  for (int t = 0; t < 60; ++t) {
    FULL_BODY(t);
  }
  FULL_BODY(60);
  // drain stage(63) (issued one tile ~1200cy ago), then barrier-free tail
  asm volatile("s_waitcnt vmcnt(0)" ::: "memory");
  __builtin_amdgcn_s_barrier();

  // tile 61
  READ8(aN, bN, 61, ps1);
  SBAR();
  MFMA16(aC, bC);
  SBAR();
  READ8(aC, bC, 62, ps0);
  SBAR();
  MFMA16(aN, bN);
  SBAR();
  // tile 62
  READ8(aN, bN, 62, ps1);
  SBAR();
  MFMA16(aC, bC);
  SBAR();
  READ8(aC, bC, 63, ps0);
  SBAR();
  MFMA16(aN, bN);
  SBAR();
  // tile 63
  READ8(aN, bN, 63, ps1);
  SBAR();
  MFMA16(aC, bC);
  SBAR();
  MFMA16(aN, bN);

  // ---- epilogue: out = is * ws[n] * acc + bias[n] -----------------------
  // C/D layout (32x32): col = lane&31, row = (r&3) + 8*(r>>2) + 4*(lane>>5)
  const float is0 = is_ptr[0];
  const int row_base = bm * BM + wm + 4 * hi;
  const int col_base = bn * BN + wn + r31;
#pragma unroll
  for (int ni = 0; ni < 4; ++ni) {
    const int col = col_base + ni * 32;
    const float s = is0 * wscale[col];
    const float b = bias[col];
#pragma unroll
    for (int mi = 0; mi < 4; ++mi) {
      const long rb = (long)(row_base + mi * 32) * NN + col;
#pragma unroll
      for (int r = 0; r < 16; ++r) {
        const int roff = (r & 3) + 8 * (r >> 2);
        out[rb + (long)roff * NN] = (float)acc[mi][ni][r] * s + b;
      }
    }
  }
#undef FULL_BODY
#undef SBAR
#undef MFMA16
#undef READ8
#undef STAGE8
}

// ---------------------------------------------------------------------------
extern "C" void kernel_launch(void* const* d_in, const int* in_sizes, int n_in,
                              void* d_out, int out_size, void* d_ws, size_t ws_size,
                              hipStream_t stream) {
  const int*   inp    = (const int*)d_in[0];    // [M,K] int32 (int8-range)
  const int*   weight = (const int*)d_in[1];    // [N,K] int32 (int8-range)
  const float* bias   = (const float*)d_in[2];  // [N]
  const float* iscale = (const float*)d_in[3];  // [1]
  const int*   izp    = (const int*)d_in[4];    // [1]
  const float* wscale = (const float*)d_in[5];  // [N]
  const int*   wzp    = (const int*)d_in[6];    // [N]
  float* out = (float*)d_out;

  char* a8 = (char*)d_ws;                        // M*K  = 33.5 MB, row-major
  char* w8 = a8 + (size_t)MM * KK;               // N*K  = 16.8 MB, row-major

  // pack: (M*K + N*K)/4 threads = 12,582,912 -> 49152 blocks of 256 (exact)
  pack_kernel<<<49152, 256, 0, stream>>>(inp, weight, a8, w8, izp, wzp);

  // GEMM: 32 * 16 = 512 blocks of 256 threads (4 waves, 1 wave/SIMD each)
  qgemm_kernel<<<512, 256, 0, stream>>>(a8, w8, out, bias, iscale, wscale);
}